// Round 2
// baseline (3326.394 us; speedup 1.0000x reference)
//
#include <hip/hip_runtime.h>
#include <math.h>

// Problem constants
#define HH 240
#define WW 320
#define HWSZ (240*320)      // 76800
#define NN 2

// Workspace layout (bytes)
#define OFF_W1T   0                  // w1t[ci][co*9+k]  : 128*576 f32
#define OFF_W3T   294912             // w3t[ci][co*9+k]  : 64*576  f32
#define OFF_W2T   442368             // w2t[c][j]        : 64*54   f32
#define OFF_COEFT 456192             // coeft[c][oc*6+m] : 64*384  f32
#define OFF_BN    554496             // [sbr(64), bbr2(64), s3(64), b3(64)]
#define OFF_U     557056             // u: 2*64*76800 f32

// ---------------- prep: weight transposes + BN folds ----------------
__global__ void prep_k(const float* __restrict__ w1, const float* __restrict__ w3,
                       const float* __restrict__ w2, const float* __restrict__ coef,
                       const float* __restrict__ coef_bias,
                       const float* __restrict__ brg, const float* __restrict__ brb,
                       const float* __restrict__ brm, const float* __restrict__ brv,
                       const float* __restrict__ g3, const float* __restrict__ b3,
                       const float* __restrict__ m3, const float* __restrict__ v3,
                       float* __restrict__ ws) {
    int id = blockIdx.x * 256 + threadIdx.x;
    if (id < 73728) {
        int ci = id / 576; int r = id - ci * 576; int co = r / 9; int k = r - co * 9;
        ws[OFF_W1T/4 + id] = w1[co*1152 + ci*9 + k];
        return;
    }
    id -= 73728;
    if (id < 36864) {
        int ci = id / 576; int r = id - ci * 576; int co = r / 9; int k = r - co * 9;
        ws[OFF_W3T/4 + id] = w3[co*576 + ci*9 + k];
        return;
    }
    id -= 36864;
    if (id < 3456) {
        int c = id / 54; int j = id - c * 54;
        ws[OFF_W2T/4 + id] = w2[j*64 + c];
        return;
    }
    id -= 3456;
    if (id < 24576) {
        int c = id / 384; int r = id - c * 384; int oc = r / 6; int m = r - oc * 6;
        ws[OFF_COEFT/4 + id] = coef[oc*384 + c*6 + m];
        return;
    }
    id -= 24576;
    if (id < 64) {
        float s = brg[id] * rsqrtf(brv[id] + 1e-5f);
        ws[OFF_BN/4 + id]      = s;
        ws[OFF_BN/4 + 64 + id] = coef_bias[id]*s + brb[id] - brm[id]*s;
        return;
    }
    id -= 64;
    if (id < 64) {
        float s = g3[id] * rsqrtf(v3[id] + 1e-5f);
        ws[OFF_BN/4 + 128 + id] = s;
        ws[OFF_BN/4 + 192 + id] = b3[id] - m3[id]*s;
    }
}

// ---------------- kernel 1: conv3x3(cat(feat,weight),128->64)+b1+ReLU -> t ----------------
// 32x8 pixel tile / block (256 thr). 16-channel LDS chunks, reg-prefetch of next chunk.
// acc[64] kept in VGPRs via __launch_bounds__(256,2).
__launch_bounds__(256, 2)
__global__ void conv1_k(const float* __restrict__ feat, const float* __restrict__ wgt,
                        const float* __restrict__ w1t, const float* __restrict__ b1,
                        float* __restrict__ tout) {
    __shared__ float tile[16 * 340];   // 16 ch x (10x34)
    const int tx = threadIdx.x, ty = threadIdx.y;
    const int x0 = blockIdx.x * 32, y0 = blockIdx.y * 8;
    const int n = blockIdx.z;
    const int x = x0 + tx, y = y0 + ty;
    const int tid = ty * 32 + tx;

    float acc[64];
    #pragma unroll
    for (int i = 0; i < 64; ++i) acc[i] = 0.f;

    float pf[22];
    auto loadc = [&](int ch) {
        const float* base = (ch < 4) ? feat + (size_t)(n*64 + ch*16) * HWSZ
                                     : wgt  + (size_t)(n*64 + (ch-4)*16) * HWSZ;
        #pragma unroll
        for (int s = 0; s < 22; ++s) {
            int idx = tid + s * 256;
            float v = 0.f;
            if (s < 21 || idx < 5440) {
                int cl = idx / 340, r = idx - cl * 340;
                int ly = r / 34, lx = r - ly * 34;
                int gy = y0 - 1 + ly, gx = x0 - 1 + lx;
                if (gy >= 0 && gy < HH && gx >= 0 && gx < WW)
                    v = base[cl * HWSZ + gy * WW + gx];
            }
            pf[s] = v;
        }
    };

    loadc(0);
    for (int ch = 0; ch < 8; ++ch) {
        __syncthreads();                       // prev chunk's readers done
        #pragma unroll
        for (int s = 0; s < 22; ++s) {
            int idx = tid + s * 256;
            if (s < 21 || idx < 5440) tile[idx] = pf[s];
        }
        __syncthreads();
        if (ch < 7) loadc(ch + 1);             // overlap next loads with compute
        const float* wch = w1t + ch * 16 * 576;
        #pragma unroll 2
        for (int cl = 0; cl < 16; ++cl) {
            float p[9];
            #pragma unroll
            for (int ky = 0; ky < 3; ++ky)
                #pragma unroll
                for (int kx = 0; kx < 3; ++kx)
                    p[ky*3 + kx] = tile[cl*340 + (ty + ky)*34 + (tx + kx)];
            const float* wci = wch + cl * 576;
            #pragma unroll
            for (int co = 0; co < 64; ++co)
                #pragma unroll
                for (int k = 0; k < 9; ++k)
                    acc[co] = fmaf(wci[co*9 + k], p[k], acc[co]);
        }
    }
    #pragma unroll
    for (int co = 0; co < 64; ++co)
        tout[(size_t)(n*64 + co) * HWSZ + y * WW + x] = fmaxf(acc[co] + b1[co], 0.f);
}

// ---------------- kernel 2: bases(1x1) + einsum + coef(1x1) + BN + ReLU -> u ----------------
__launch_bounds__(256, 2)
__global__ void fuse2_k(const float* __restrict__ feat, const float* __restrict__ tin,
                        const float* __restrict__ w2t, const float* __restrict__ b2,
                        const float* __restrict__ coeft, const float* __restrict__ bn,
                        float* __restrict__ uout) {
    __shared__ float tile[16 * 340];
    const int tx = threadIdx.x, ty = threadIdx.y;
    const int x0 = blockIdx.x * 32, y0 = blockIdx.y * 8;
    const int n = blockIdx.z;
    const int x = x0 + tx, y = y0 + ty;
    const int tid = ty * 32 + tx;

    float pf[22];
    auto loadc = [&](int ch) {
        const float* base = feat + (size_t)(n*64 + ch*16) * HWSZ;
        #pragma unroll
        for (int s = 0; s < 22; ++s) {
            int idx = tid + s * 256;
            float v = 0.f;
            if (s < 21 || idx < 5440) {
                int cl = idx / 340, r = idx - cl * 340;
                int ly = r / 34, lx = r - ly * 34;
                int gy = y0 - 1 + ly, gx = x0 - 1 + lx;
                if (gy >= 0 && gy < HH && gx >= 0 && gx < WW)
                    v = base[cl * HWSZ + gy * WW + gx];
            }
            pf[s] = v;
        }
    };

    loadc(0);   // overlap chunk-0 loads with phase A

    // Phase A: bases[j] = b2[j] + sum_c w2[j,c] * t[c]
    float bases[54];
    #pragma unroll
    for (int j = 0; j < 54; ++j) bases[j] = b2[j];
    for (int c = 0; c < 64; ++c) {
        float tv = tin[(size_t)(n*64 + c) * HWSZ + y * WW + x];
        const float* w2c = w2t + c * 54;
        #pragma unroll
        for (int j = 0; j < 54; ++j) bases[j] = fmaf(w2c[j], tv, bases[j]);
    }

    float out[64];
    #pragma unroll
    for (int i = 0; i < 64; ++i) out[i] = 0.f;

    for (int ch = 0; ch < 4; ++ch) {
        __syncthreads();
        #pragma unroll
        for (int s = 0; s < 22; ++s) {
            int idx = tid + s * 256;
            if (s < 21 || idx < 5440) tile[idx] = pf[s];
        }
        __syncthreads();
        if (ch < 3) loadc(ch + 1);
        #pragma unroll 2
        for (int cl = 0; cl < 16; ++cl) {
            float p[9];
            #pragma unroll
            for (int ky = 0; ky < 3; ++ky)
                #pragma unroll
                for (int kx = 0; kx < 3; ++kx)
                    p[ky*3 + kx] = tile[cl*340 + (ty + ky)*34 + (tx + kx)];
            float s6[6];
            #pragma unroll
            for (int m = 0; m < 6; ++m) {
                float a = 0.f;
                #pragma unroll
                for (int l = 0; l < 9; ++l) a = fmaf(bases[m*9 + l], p[l], a);
                s6[m] = a;
            }
            const float* cf = coeft + (ch*16 + cl) * 384;
            #pragma unroll
            for (int oc = 0; oc < 64; ++oc)
                #pragma unroll
                for (int m = 0; m < 6; ++m)
                    out[oc] = fmaf(cf[oc*6 + m], s6[m], out[oc]);
        }
    }

    #pragma unroll
    for (int oc = 0; oc < 64; ++oc) {
        float v = fmaxf(fmaf(out[oc], bn[oc], bn[64 + oc]), 0.f);
        uout[(size_t)(n*64 + oc) * HWSZ + y * WW + x] = v;
    }
}

// ---------------- kernel 3: conv3x3(u,64->64) + BN + ReLU -> d_out ----------------
__launch_bounds__(256, 2)
__global__ void conv3_k(const float* __restrict__ uin, const float* __restrict__ w3t,
                        const float* __restrict__ bn, float* __restrict__ outp) {
    __shared__ float tile[16 * 340];
    const int tx = threadIdx.x, ty = threadIdx.y;
    const int x0 = blockIdx.x * 32, y0 = blockIdx.y * 8;
    const int n = blockIdx.z;
    const int x = x0 + tx, y = y0 + ty;
    const int tid = ty * 32 + tx;

    float acc[64];
    #pragma unroll
    for (int i = 0; i < 64; ++i) acc[i] = 0.f;

    float pf[22];
    auto loadc = [&](int ch) {
        const float* base = uin + (size_t)(n*64 + ch*16) * HWSZ;
        #pragma unroll
        for (int s = 0; s < 22; ++s) {
            int idx = tid + s * 256;
            float v = 0.f;
            if (s < 21 || idx < 5440) {
                int cl = idx / 340, r = idx - cl * 340;
                int ly = r / 34, lx = r - ly * 34;
                int gy = y0 - 1 + ly, gx = x0 - 1 + lx;
                if (gy >= 0 && gy < HH && gx >= 0 && gx < WW)
                    v = base[cl * HWSZ + gy * WW + gx];
            }
            pf[s] = v;
        }
    };

    loadc(0);
    for (int ch = 0; ch < 4; ++ch) {
        __syncthreads();
        #pragma unroll
        for (int s = 0; s < 22; ++s) {
            int idx = tid + s * 256;
            if (s < 21 || idx < 5440) tile[idx] = pf[s];
        }
        __syncthreads();
        if (ch < 3) loadc(ch + 1);
        const float* wch = w3t + ch * 16 * 576;
        #pragma unroll 2
        for (int cl = 0; cl < 16; ++cl) {
            float p[9];
            #pragma unroll
            for (int ky = 0; ky < 3; ++ky)
                #pragma unroll
                for (int kx = 0; kx < 3; ++kx)
                    p[ky*3 + kx] = tile[cl*340 + (ty + ky)*34 + (tx + kx)];
            const float* wci = wch + cl * 576;
            #pragma unroll
            for (int co = 0; co < 64; ++co)
                #pragma unroll
                for (int k = 0; k < 9; ++k)
                    acc[co] = fmaf(wci[co*9 + k], p[k], acc[co]);
        }
    }
    #pragma unroll
    for (int co = 0; co < 64; ++co) {
        float v = fmaxf(fmaf(acc[co], bn[128 + co], bn[192 + co]), 0.f);
        outp[(size_t)(n*64 + co) * HWSZ + y * WW + x] = v;
    }
}

extern "C" void kernel_launch(void* const* d_in, const int* in_sizes, int n_in,
                              void* d_out, int out_size, void* d_ws, size_t ws_size,
                              hipStream_t stream) {
    const float* feat      = (const float*)d_in[0];
    const float* wgt       = (const float*)d_in[1];
    const float* w1        = (const float*)d_in[2];
    const float* b1        = (const float*)d_in[3];
    const float* w2        = (const float*)d_in[4];
    const float* b2        = (const float*)d_in[5];
    const float* coef      = (const float*)d_in[6];
    const float* coef_bias = (const float*)d_in[7];
    const float* brg       = (const float*)d_in[8];
    const float* brb       = (const float*)d_in[9];
    const float* brm       = (const float*)d_in[10];
    const float* brv       = (const float*)d_in[11];
    const float* w3        = (const float*)d_in[12];
    const float* g3        = (const float*)d_in[13];
    const float* b3        = (const float*)d_in[14];
    const float* m3        = (const float*)d_in[15];
    const float* v3        = (const float*)d_in[16];

    float* out = (float*)d_out;
    float* ws  = (float*)d_ws;

    prep_k<<<542, 256, 0, stream>>>(w1, w3, w2, coef, coef_bias,
                                    brg, brb, brm, brv, g3, b3, m3, v3, ws);

    dim3 grid(WW/32, HH/8, NN);   // (10, 30, 2)
    dim3 blk(32, 8);

    conv1_k<<<grid, blk, 0, stream>>>(feat, wgt, ws + OFF_W1T/4, b1, out);
    fuse2_k<<<grid, blk, 0, stream>>>(feat, out, ws + OFF_W2T/4, b2,
                                      ws + OFF_COEFT/4, ws + OFF_BN/4, ws + OFF_U/4);
    conv3_k<<<grid, blk, 0, stream>>>(ws + OFF_U/4, ws + OFF_W3T/4, ws + OFF_BN/4, out);
}

// Round 3
// 569.972 us; speedup vs baseline: 5.8361x; 5.8361x over previous
//
#include <hip/hip_runtime.h>
#include <math.h>

#define HH 240
#define WW 320
#define HWSZ (240*320)
#define NN 2

// Workspace layout (bytes)
#define OFF_BW1   0         // conv1 weight frags: 4cc*9t*4m*2half*64lane*8 bf16 = 294912 B
#define OFF_BW3   294912    // conv3 weight frags: 2cc*9t*4m*2half*64lane*8 bf16 = 147456 B
#define OFF_W2T   442368    // w2t[c][j] f32: 64*54
#define OFF_COEFT 456192    // coeft[c][oc*6+m] f32: 64*384
#define OFF_BN    554496    // [sbr(64), bbr2(64), s3(64), o3(64)] f32
#define OFF_U     557056    // u: 2*64*76800 f32

typedef __attribute__((ext_vector_type(8))) short short8v;
typedef __attribute__((ext_vector_type(4))) float f32x4;

__device__ __forceinline__ unsigned short bhi(float x) {
    union { float f; unsigned u; } c; c.f = x; return (unsigned short)(c.u >> 16);
}
__device__ __forceinline__ float bf2f(unsigned short h) {
    union { float f; unsigned u; } c; c.u = ((unsigned)h) << 16; return c.f;
}

// ---------------- prep: weight frag packing + transposes + BN folds ----------------
// tasks: B1 frags 18432, B3 frags 9216, w2t 3456, coeft 24576, bn 128  => 55808 = 218*256
__global__ void prep_k(const float* __restrict__ w1, const float* __restrict__ w3,
                       const float* __restrict__ w2, const float* __restrict__ coef,
                       const float* __restrict__ coef_bias,
                       const float* __restrict__ brg, const float* __restrict__ brb,
                       const float* __restrict__ brm, const float* __restrict__ brv,
                       const float* __restrict__ g3, const float* __restrict__ b3,
                       const float* __restrict__ m3, const float* __restrict__ v3,
                       float* __restrict__ ws) {
    int id = blockIdx.x * 256 + threadIdx.x;
    unsigned short* bw = (unsigned short*)ws;

    if (id < 18432) {   // conv1 weight frags: lane task writes 8 bf16 (16B)
        int l = id & 63; int f = id >> 6;
        int half = f & 1; f >>= 1;
        int m = f & 3;    f >>= 2;        // f in 0..35
        int t = f % 9, cc = f / 9;
        unsigned short v16[8];
        #pragma unroll
        for (int j = 0; j < 8; ++j) {
            int ci = cc*32 + (l>>4)*8 + j;
            int co = m*16 + (l&15);
            float v = w1[(co*128 + ci)*9 + t];
            unsigned short hi = bhi(v);
            v16[j] = half ? bhi(v - bf2f(hi)) : hi;
        }
        int fragidx = ((cc*9 + t)*4 + m)*2 + half;
        unsigned short* dst = bw + (size_t)fragidx*512 + l*8;
        #pragma unroll
        for (int j = 0; j < 8; ++j) dst[j] = v16[j];
        return;
    }
    id -= 18432;
    if (id < 9216) {    // conv3 weight frags
        int l = id & 63; int f = id >> 6;
        int half = f & 1; f >>= 1;
        int m = f & 3;    f >>= 2;        // f in 0..17
        int t = f % 9, cc = f / 9;
        unsigned short v16[8];
        #pragma unroll
        for (int j = 0; j < 8; ++j) {
            int ci = cc*32 + (l>>4)*8 + j;
            int co = m*16 + (l&15);
            float v = w3[(co*64 + ci)*9 + t];
            unsigned short hi = bhi(v);
            v16[j] = half ? bhi(v - bf2f(hi)) : hi;
        }
        int fragidx = ((cc*9 + t)*4 + m)*2 + half;
        unsigned short* dst = bw + OFF_BW3/2 + (size_t)fragidx*512 + l*8;
        #pragma unroll
        for (int j = 0; j < 8; ++j) dst[j] = v16[j];
        return;
    }
    id -= 9216;
    if (id < 3456) {    // w2t[c*54+j] = w2[j*64+c]
        int c = id / 54, j = id - c*54;
        ws[OFF_W2T/4 + id] = w2[j*64 + c];
        return;
    }
    id -= 3456;
    if (id < 24576) {   // coeft[c*384 + oc*6 + m] = coef[oc*384 + c*6 + m]
        int c = id / 384; int r = id - c*384; int oc = r / 6; int m = r - oc*6;
        ws[OFF_COEFT/4 + id] = coef[oc*384 + c*6 + m];
        return;
    }
    id -= 24576;
    if (id < 64) {
        float s = brg[id] * rsqrtf(brv[id] + 1e-5f);
        ws[OFF_BN/4 + id]      = s;
        ws[OFF_BN/4 + 64 + id] = coef_bias[id]*s + brb[id] - brm[id]*s;
        return;
    }
    id -= 64;
    if (id < 64) {
        float s = g3[id] * rsqrtf(v3[id] + 1e-5f);
        ws[OFF_BN/4 + 128 + id] = s;
        ws[OFF_BN/4 + 192 + id] = b3[id] - m3[id]*s;
    }
}

// ---------------- MFMA conv 3x3 (CHUNKS*32 -> 64 ch) ----------------
// block: 256 thr = 4 waves; pixel tile 8 rows x 32 cols.
// wave w owns 4 pixel-frags (rows 2w,2w+1 x two 16-px halves) x 4 co-frags.
// LDS: [py 10][px 34][ci 32] bf16 hi/lo, 80B padded rows (conflict-free b128 reads).
// weights = MFMA A operand (frags pre-packed in ws, global double-buffered).
// 3-pass split bf16: acc += Whi*Phi + Wlo*Phi + Whi*Plo.
template<int CHUNKS, bool HAS_SCALE>
__launch_bounds__(256, 2)
__global__ void convmfma_k(const float* __restrict__ in0, const float* __restrict__ in1,
                           const unsigned short* __restrict__ wfr,
                           const float* __restrict__ epiA, const float* __restrict__ epiB,
                           float* __restrict__ outp) {
    __shared__ unsigned long long AHI[3400], ALO[3400];   // 27200 B each
    const int tid = threadIdx.x;
    const int lane = tid & 63, wv = tid >> 6;
    const int l15 = lane & 15, l4 = lane >> 4;
    const int x0 = blockIdx.x * 32, y0 = blockIdx.y * 8;
    const int nb = blockIdx.z;

    f32x4 acc[4][4];
    #pragma unroll
    for (int m = 0; m < 4; ++m)
        #pragma unroll
        for (int nf = 0; nf < 4; ++nf)
            acc[m][nf] = (f32x4){0.f, 0.f, 0.f, 0.f};

    short8v WHf[2][4], WLf[2][4];
    auto loadW = [&](int g, int b) {
        int cc = g / 9, t = g - cc*9;
        #pragma unroll
        for (int m = 0; m < 4; ++m) {
            const unsigned short* p = wfr + (size_t)(((cc*9 + t)*4 + m)*2)*512 + lane*8;
            WHf[b][m] = *(const short8v*)p;
            WLf[b][m] = *(const short8v*)(p + 512);
        }
    };
    loadW(0, 0);

    const char* AHIb = (const char*)AHI;
    const char* ALOb = (const char*)ALO;

    #pragma unroll
    for (int cc = 0; cc < CHUNKS; ++cc) {
        __syncthreads();
        const float* plane = (cc < 2) ? in0 + (size_t)(nb*64 + cc*32) * HWSZ
                                      : in1 + (size_t)(nb*64 + (cc-2)*32) * HWSZ;
        #pragma unroll
        for (int it = 0; it < 11; ++it) {
            int i = tid + it * 256;
            if (i < 2720) {
                int q = i / 340, p = i - q*340;
                int py = p / 34, px = p - py*34;
                int gy = y0 - 1 + py, gx = x0 - 1 + px;
                bool ok = (gy >= 0) & (gy < HH) & (gx >= 0) & (gx < WW);
                const float* sp = plane + (size_t)(q*4) * HWSZ + gy*WW + gx;
                unsigned long long Hv = 0, Lv = 0;
                #pragma unroll
                for (int d = 0; d < 4; ++d) {
                    float v = ok ? sp[(size_t)d * HWSZ] : 0.f;
                    unsigned short h = bhi(v);
                    unsigned short lo = bhi(v - bf2f(h));
                    Hv |= ((unsigned long long)h)  << (16*d);
                    Lv |= ((unsigned long long)lo) << (16*d);
                }
                int widx = (py*34 + px)*10 + q;     // 80B rows = 10 ull
                AHI[widx] = Hv;
                ALO[widx] = Lv;
            }
        }
        __syncthreads();
        #pragma unroll
        for (int t = 0; t < 9; ++t) {
            int g = cc*9 + t;
            int b = g & 1;
            if (g + 1 < CHUNKS*9) loadW(g + 1, b ^ 1);
            int ky = t / 3, kx = t - ky*3;
            #pragma unroll
            for (int nf = 0; nf < 4; ++nf) {
                int gnf = wv*4 + nf;
                int r = gnf >> 1, h = gnf & 1;
                int off = ((r + ky)*34 + 16*h + l15 + kx)*80 + l4*16;
                short8v Ph = *(const short8v*)(AHIb + off);
                short8v Pl = *(const short8v*)(ALOb + off);
                #pragma unroll
                for (int m = 0; m < 4; ++m) {
                    acc[m][nf] = __builtin_amdgcn_mfma_f32_16x16x32_bf16(WHf[b][m], Ph, acc[m][nf], 0, 0, 0);
                    acc[m][nf] = __builtin_amdgcn_mfma_f32_16x16x32_bf16(WLf[b][m], Ph, acc[m][nf], 0, 0, 0);
                    acc[m][nf] = __builtin_amdgcn_mfma_f32_16x16x32_bf16(WHf[b][m], Pl, acc[m][nf], 0, 0, 0);
                }
            }
        }
    }

    // epilogue: D row = co (16m + 4*l4 + i), col = px (l15)
    #pragma unroll
    for (int m = 0; m < 4; ++m) {
        #pragma unroll
        for (int i = 0; i < 4; ++i) {
            int co = m*16 + l4*4 + i;
            float sc  = HAS_SCALE ? epiA[co] : 1.0f;
            float ofs = HAS_SCALE ? epiB[co] : epiA[co];
            float* op = outp + (size_t)(nb*64 + co) * HWSZ;
            #pragma unroll
            for (int nf = 0; nf < 4; ++nf) {
                int gnf = wv*4 + nf;
                int r = gnf >> 1, h = gnf & 1;
                int y = y0 + r, x = x0 + 16*h + l15;
                op[y*WW + x] = fmaxf(acc[m][nf][i]*sc + ofs, 0.f);
            }
        }
    }
}

// ---------------- kernel 2: bases(1x1) + einsum + coef(1x1) + BN + ReLU -> u ----------------
__launch_bounds__(256)
__global__ void fuse2_k(const float* __restrict__ feat, const float* __restrict__ tin,
                        const float* __restrict__ w2t, const float* __restrict__ b2,
                        const float* __restrict__ coeft, const float* __restrict__ bn,
                        float* __restrict__ uout) {
    __shared__ float smem[16 * 340];
    const int tx = threadIdx.x, ty = threadIdx.y;
    const int x0 = blockIdx.x * 32, y0 = blockIdx.y * 8;
    const int n = blockIdx.z;
    const int x = x0 + tx, y = y0 + ty;
    const int tid = ty * 32 + tx;

    float bases[54];
    #pragma unroll
    for (int j = 0; j < 54; ++j) bases[j] = b2[j];
    for (int c = 0; c < 64; ++c) {
        float tv = tin[(size_t)(n*64 + c) * HWSZ + y * WW + x];
        const float* w2c = w2t + c * 54;
        #pragma unroll
        for (int j = 0; j < 54; ++j) bases[j] = fmaf(w2c[j], tv, bases[j]);
    }

    float out[64];
    #pragma unroll
    for (int i = 0; i < 64; ++i) out[i] = 0.f;

    for (int cc = 0; cc < 64; cc += 16) {
        __syncthreads();
        for (int i = tid; i < 16 * 340; i += 256) {
            int cl = i / 340; int r = i - cl * 340;
            int ly = r / 34, lx = r - ly * 34;
            int gy = y0 - 1 + ly, gx = x0 - 1 + lx;
            float v = 0.f;
            if (gy >= 0 && gy < HH && gx >= 0 && gx < WW)
                v = feat[(size_t)(n*64 + cc + cl) * HWSZ + gy * WW + gx];
            smem[i] = v;
        }
        __syncthreads();
        for (int cl = 0; cl < 16; ++cl) {
            float p[9];
            #pragma unroll
            for (int ky = 0; ky < 3; ++ky)
                #pragma unroll
                for (int kx = 0; kx < 3; ++kx)
                    p[ky*3 + kx] = smem[cl*340 + (ty + ky)*34 + tx + kx];
            float s6[6];
            #pragma unroll
            for (int m = 0; m < 6; ++m) {
                float a = 0.f;
                #pragma unroll
                for (int l = 0; l < 9; ++l) a = fmaf(bases[m*9 + l], p[l], a);
                s6[m] = a;
            }
            const float* cf = coeft + (cc + cl) * 384;
            #pragma unroll
            for (int oc = 0; oc < 64; ++oc)
                #pragma unroll
                for (int m = 0; m < 6; ++m)
                    out[oc] = fmaf(cf[oc*6 + m], s6[m], out[oc]);
        }
    }

    #pragma unroll
    for (int oc = 0; oc < 64; ++oc) {
        float v = fmaxf(fmaf(out[oc], bn[oc], bn[64 + oc]), 0.f);
        uout[(size_t)(n*64 + oc) * HWSZ + y * WW + x] = v;
    }
}

extern "C" void kernel_launch(void* const* d_in, const int* in_sizes, int n_in,
                              void* d_out, int out_size, void* d_ws, size_t ws_size,
                              hipStream_t stream) {
    const float* feat      = (const float*)d_in[0];
    const float* wgt       = (const float*)d_in[1];
    const float* w1        = (const float*)d_in[2];
    const float* b1        = (const float*)d_in[3];
    const float* w2        = (const float*)d_in[4];
    const float* b2        = (const float*)d_in[5];
    const float* coef      = (const float*)d_in[6];
    const float* coef_bias = (const float*)d_in[7];
    const float* brg       = (const float*)d_in[8];
    const float* brb       = (const float*)d_in[9];
    const float* brm       = (const float*)d_in[10];
    const float* brv       = (const float*)d_in[11];
    const float* w3        = (const float*)d_in[12];
    const float* g3        = (const float*)d_in[13];
    const float* b3        = (const float*)d_in[14];
    const float* m3        = (const float*)d_in[15];
    const float* v3        = (const float*)d_in[16];

    float* out = (float*)d_out;
    float* ws  = (float*)d_ws;

    prep_k<<<218, 256, 0, stream>>>(w1, w3, w2, coef, coef_bias,
                                    brg, brb, brm, brv, g3, b3, m3, v3, ws);

    dim3 grid(WW/32, HH/8, NN);   // (10, 30, 2)

    // conv1: t -> d_out
    convmfma_k<4, false><<<grid, 256, 0, stream>>>(
        feat, wgt, (const unsigned short*)ws, b1, b1, out);

    // fuse2: u -> ws
    dim3 blk2(32, 8);
    fuse2_k<<<grid, blk2, 0, stream>>>(feat, out, ws + OFF_W2T/4, b2,
                                       ws + OFF_COEFT/4, ws + OFF_BN/4, ws + OFF_U/4);

    // conv3: d_out
    convmfma_k<2, true><<<grid, 256, 0, stream>>>(
        ws + OFF_U/4, ws + OFF_U/4,
        (const unsigned short*)((const char*)ws + OFF_BW3),
        ws + OFF_BN/4 + 128, ws + OFF_BN/4 + 192, out);
}

// Round 4
// 257.218 us; speedup vs baseline: 12.9322x; 2.2159x over previous
//
#include <hip/hip_runtime.h>
#include <math.h>

#define HH 240
#define WW 320
#define HWSZ (240*320)
#define NN 2

// Workspace layout (bytes)
#define OFF_BW1   0         // conv1 weight frags: 294912 B
#define OFF_BW3   294912    // conv3 weight frags: 147456 B
#define OFF_W2A   442368    // bases-GEMM A frags: 2kc*4mf*64lane*8 bf16 = 8192 B
#define OFF_COEFA 450560    // coef-GEMM A frags: 4cg*3ch*4oc*64lane*8 bf16 = 49152 B
#define OFF_BN    499712    // [sbr(64), bbr2(64), s3(64), o3(64)] f32
#define OFF_U     500736    // u: 2*64*76800 f32

typedef __attribute__((ext_vector_type(8))) short short8v;
typedef __attribute__((ext_vector_type(4))) float f32x4;

__device__ __forceinline__ unsigned short bhi(float x) {
    union { float f; unsigned u; } c; c.f = x; return (unsigned short)(c.u >> 16);
}
__device__ __forceinline__ float bf2f(unsigned short h) {
    union { float f; unsigned u; } c; c.u = ((unsigned)h) << 16; return c.f;
}

// ---------------- prep: weight frag packing + BN folds ----------------
// tasks: BW1 18432, BW3 9216, W2A 512, COEFA 3072, bn 128 => 31360 -> 123 blocks
__global__ void prep_k(const float* __restrict__ w1, const float* __restrict__ w3,
                       const float* __restrict__ w2, const float* __restrict__ coef,
                       const float* __restrict__ coef_bias,
                       const float* __restrict__ brg, const float* __restrict__ brb,
                       const float* __restrict__ brm, const float* __restrict__ brv,
                       const float* __restrict__ g3, const float* __restrict__ b3,
                       const float* __restrict__ m3, const float* __restrict__ v3,
                       float* __restrict__ ws) {
    int id = blockIdx.x * 256 + threadIdx.x;
    unsigned short* bw = (unsigned short*)ws;

    if (id < 18432) {   // conv1 weight frags (split hi/lo)
        int l = id & 63; int f = id >> 6;
        int half = f & 1; f >>= 1;
        int m = f & 3;    f >>= 2;
        int t = f % 9, cc = f / 9;
        unsigned short v16[8];
        #pragma unroll
        for (int j = 0; j < 8; ++j) {
            int ci = cc*32 + (l>>4)*8 + j;
            int co = m*16 + (l&15);
            float v = w1[(co*128 + ci)*9 + t];
            unsigned short hi = bhi(v);
            v16[j] = half ? bhi(v - bf2f(hi)) : hi;
        }
        unsigned short* dst = bw + (size_t)(((cc*9 + t)*4 + m)*2 + half)*512 + l*8;
        #pragma unroll
        for (int j = 0; j < 8; ++j) dst[j] = v16[j];
        return;
    }
    id -= 18432;
    if (id < 9216) {    // conv3 weight frags (split hi/lo)
        int l = id & 63; int f = id >> 6;
        int half = f & 1; f >>= 1;
        int m = f & 3;    f >>= 2;
        int t = f % 9, cc = f / 9;
        unsigned short v16[8];
        #pragma unroll
        for (int j = 0; j < 8; ++j) {
            int ci = cc*32 + (l>>4)*8 + j;
            int co = m*16 + (l&15);
            float v = w3[(co*64 + ci)*9 + t];
            unsigned short hi = bhi(v);
            v16[j] = half ? bhi(v - bf2f(hi)) : hi;
        }
        unsigned short* dst = bw + OFF_BW3/2 + (size_t)(((cc*9 + t)*4 + m)*2 + half)*512 + l*8;
        #pragma unroll
        for (int j = 0; j < 8; ++j) dst[j] = v16[j];
        return;
    }
    id -= 9216;
    if (id < 512) {     // W2A: bases-GEMM A frags. A[row=out_j 54pad64][k=c 64]
        int l = id & 63; int f = id >> 6;   // f in 0..7
        int mf = f & 3, kc = f >> 2;
        int row = mf*16 + (l & 15);
        unsigned short* dst = bw + OFF_W2A/2 + (size_t)((kc*4 + mf)*64 + l)*8;
        #pragma unroll
        for (int j = 0; j < 8; ++j) {
            int k = kc*32 + (l>>4)*8 + j;
            float v = (row < 54) ? w2[row*64 + k] : 0.f;
            dst[j] = bhi(v);
        }
        return;
    }
    id -= 512;
    if (id < 3072) {    // COEFA: coef-GEMM A frags. k-order: cg*96 + (m_local*16+cl)
        int l = id & 63; int f = id >> 6;   // f in 0..47
        int ocf = f & 3; int g2 = f >> 2;   // g2 = cg*3 + ch
        int ch = g2 % 3, cg = g2 / 3;
        int oc = ocf*16 + (l & 15);
        unsigned short* dst = bw + OFF_COEFA/2 + (size_t)((g2*4 + ocf)*64 + l)*8;
        #pragma unroll
        for (int j = 0; j < 8; ++j) {
            int k32 = (l>>4)*8 + j;
            int m = ch*2 + (k32 >> 4);
            int c = cg*16 + (k32 & 15);
            dst[j] = bhi(coef[oc*384 + c*6 + m]);
        }
        return;
    }
    id -= 3072;
    if (id < 64) {
        float s = brg[id] * rsqrtf(brv[id] + 1e-5f);
        ws[OFF_BN/4 + id]      = s;
        ws[OFF_BN/4 + 64 + id] = coef_bias[id]*s + brb[id] - brm[id]*s;
        return;
    }
    id -= 64;
    if (id < 64) {
        float s = g3[id] * rsqrtf(v3[id] + 1e-5f);
        ws[OFF_BN/4 + 128 + id] = s;
        ws[OFF_BN/4 + 192 + id] = b3[id] - m3[id]*s;
    }
}

// ---------------- MFMA conv 3x3 (unchanged from round 3) ----------------
template<int CHUNKS, bool HAS_SCALE>
__launch_bounds__(256, 2)
__global__ void convmfma_k(const float* __restrict__ in0, const float* __restrict__ in1,
                           const unsigned short* __restrict__ wfr,
                           const float* __restrict__ epiA, const float* __restrict__ epiB,
                           float* __restrict__ outp) {
    __shared__ unsigned long long AHI[3400], ALO[3400];
    const int tid = threadIdx.x;
    const int lane = tid & 63, wv = tid >> 6;
    const int l15 = lane & 15, l4 = lane >> 4;
    const int x0 = blockIdx.x * 32, y0 = blockIdx.y * 8;
    const int nb = blockIdx.z;

    f32x4 acc[4][4];
    #pragma unroll
    for (int m = 0; m < 4; ++m)
        #pragma unroll
        for (int nf = 0; nf < 4; ++nf)
            acc[m][nf] = (f32x4){0.f, 0.f, 0.f, 0.f};

    short8v WHf[2][4], WLf[2][4];
    auto loadW = [&](int g, int b) {
        int cc = g / 9, t = g - cc*9;
        #pragma unroll
        for (int m = 0; m < 4; ++m) {
            const unsigned short* p = wfr + (size_t)(((cc*9 + t)*4 + m)*2)*512 + lane*8;
            WHf[b][m] = *(const short8v*)p;
            WLf[b][m] = *(const short8v*)(p + 512);
        }
    };
    loadW(0, 0);

    const char* AHIb = (const char*)AHI;
    const char* ALOb = (const char*)ALO;

    #pragma unroll
    for (int cc = 0; cc < CHUNKS; ++cc) {
        __syncthreads();
        const float* plane = (cc < 2) ? in0 + (size_t)(nb*64 + cc*32) * HWSZ
                                      : in1 + (size_t)(nb*64 + (cc-2)*32) * HWSZ;
        #pragma unroll
        for (int it = 0; it < 11; ++it) {
            int i = tid + it * 256;
            if (i < 2720) {
                int q = i / 340, p = i - q*340;
                int py = p / 34, px = p - py*34;
                int gy = y0 - 1 + py, gx = x0 - 1 + px;
                bool ok = (gy >= 0) & (gy < HH) & (gx >= 0) & (gx < WW);
                const float* sp = plane + (size_t)(q*4) * HWSZ + gy*WW + gx;
                unsigned long long Hv = 0, Lv = 0;
                #pragma unroll
                for (int d = 0; d < 4; ++d) {
                    float v = ok ? sp[(size_t)d * HWSZ] : 0.f;
                    unsigned short h = bhi(v);
                    unsigned short lo = bhi(v - bf2f(h));
                    Hv |= ((unsigned long long)h)  << (16*d);
                    Lv |= ((unsigned long long)lo) << (16*d);
                }
                int widx = (py*34 + px)*10 + q;
                AHI[widx] = Hv;
                ALO[widx] = Lv;
            }
        }
        __syncthreads();
        #pragma unroll
        for (int t = 0; t < 9; ++t) {
            int g = cc*9 + t;
            int b = g & 1;
            if (g + 1 < CHUNKS*9) loadW(g + 1, b ^ 1);
            int ky = t / 3, kx = t - ky*3;
            #pragma unroll
            for (int nf = 0; nf < 4; ++nf) {
                int gnf = wv*4 + nf;
                int r = gnf >> 1, h = gnf & 1;
                int off = ((r + ky)*34 + 16*h + l15 + kx)*80 + l4*16;
                short8v Ph = *(const short8v*)(AHIb + off);
                short8v Pl = *(const short8v*)(ALOb + off);
                #pragma unroll
                for (int m = 0; m < 4; ++m) {
                    acc[m][nf] = __builtin_amdgcn_mfma_f32_16x16x32_bf16(WHf[b][m], Ph, acc[m][nf], 0, 0, 0);
                    acc[m][nf] = __builtin_amdgcn_mfma_f32_16x16x32_bf16(WLf[b][m], Ph, acc[m][nf], 0, 0, 0);
                    acc[m][nf] = __builtin_amdgcn_mfma_f32_16x16x32_bf16(WHf[b][m], Pl, acc[m][nf], 0, 0, 0);
                }
            }
        }
    }

    #pragma unroll
    for (int m = 0; m < 4; ++m) {
        #pragma unroll
        for (int i = 0; i < 4; ++i) {
            int co = m*16 + l4*4 + i;
            float sc  = HAS_SCALE ? epiA[co] : 1.0f;
            float ofs = HAS_SCALE ? epiB[co] : epiA[co];
            float* op = outp + (size_t)(nb*64 + co) * HWSZ;
            #pragma unroll
            for (int nf = 0; nf < 4; ++nf) {
                int gnf = wv*4 + nf;
                int r = gnf >> 1, h = gnf & 1;
                int y = y0 + r, x = x0 + 16*h + l15;
                op[y*WW + x] = fmaxf(acc[m][nf][i]*sc + ofs, 0.f);
            }
        }
    }
}

// ---------------- kernel 2 (MFMA): bases + einsum + coef + BN + ReLU -> u ----------------
// Phase A: bases = w2 @ t via MFMA (1-pass bf16), -> BSH (wave-private px ranges).
// Phase B: per 16-ch group: stage patches f32 in LDS; VALU computes each lane's
//          8 B-frag K-elements s[k]=sum_l bases*patch; MFMA with pre-packed coef A-frags.
__launch_bounds__(256, 2)
__global__ void fuse2_k(const float* __restrict__ feat, const float* __restrict__ tin,
                        const unsigned short* __restrict__ w2a,
                        const float* __restrict__ b2,
                        const unsigned short* __restrict__ coefa,
                        const float* __restrict__ bn,
                        float* __restrict__ uout) {
    __shared__ unsigned short BSH[256*56];   // bases bf16 [px][54 pad 56]
    __shared__ float PT[340*20];             // patches f32 [pos][16 ch pad 20] (80B rows)
    const int tid = threadIdx.x;
    const int lane = tid & 63, wv = tid >> 6;
    const int l15 = lane & 15, l4 = lane >> 4;
    const int x0 = blockIdx.x*32, y0 = blockIdx.y*8;
    const int nb = blockIdx.z;

    // ---- Phase A: bases ----
    short8v w2f[2][4];
    #pragma unroll
    for (int kc = 0; kc < 2; ++kc)
        #pragma unroll
        for (int mf = 0; mf < 4; ++mf)
            w2f[kc][mf] = *(const short8v*)(w2a + (size_t)((kc*4 + mf)*64 + lane)*8);

    f32x4 b2v[4];
    #pragma unroll
    for (int mf = 0; mf < 4; ++mf)
        #pragma unroll
        for (int i = 0; i < 4; ++i) {
            int row = mf*16 + l4*4 + i;
            b2v[mf][i] = (row < 54) ? b2[row] : 0.f;
        }

    #pragma unroll
    for (int nf = 0; nf < 4; ++nf) {
        int gnf = wv*4 + nf, r = gnf >> 1, h = gnf & 1;
        int y = y0 + r, x = x0 + 16*h + l15;
        const float* tp = tin + (size_t)nb*64*HWSZ + y*WW + x;
        short8v tf0, tf1;
        #pragma unroll
        for (int j = 0; j < 8; ++j) {
            tf0[j] = (short)bhi(tp[(size_t)(l4*8 + j) * HWSZ]);
            tf1[j] = (short)bhi(tp[(size_t)(32 + l4*8 + j) * HWSZ]);
        }
        int px = r*32 + 16*h + l15;
        #pragma unroll
        for (int mf = 0; mf < 4; ++mf) {
            f32x4 ab = (f32x4){0.f, 0.f, 0.f, 0.f};
            ab = __builtin_amdgcn_mfma_f32_16x16x32_bf16(w2f[0][mf], tf0, ab, 0, 0, 0);
            ab = __builtin_amdgcn_mfma_f32_16x16x32_bf16(w2f[1][mf], tf1, ab, 0, 0, 0);
            if (mf < 3 || l4 < 2) {
                unsigned long long w = 0;
                #pragma unroll
                for (int i = 0; i < 4; ++i)
                    w |= ((unsigned long long)bhi(ab[i] + b2v[mf][i])) << (16*i);
                *(unsigned long long*)&BSH[px*56 + mf*16 + l4*4] = w;   // wave-private px
            }
        }
    }

    // ---- Phase B ----
    f32x4 acc[4][4];
    #pragma unroll
    for (int m = 0; m < 4; ++m)
        #pragma unroll
        for (int nf = 0; nf < 4; ++nf)
            acc[m][nf] = (f32x4){0.f, 0.f, 0.f, 0.f};

    const int c0 = (l4 & 1) * 8;
    const int m0 = l4 >> 1;

    #pragma unroll 1
    for (int cg = 0; cg < 4; ++cg) {
        __syncthreads();
        #pragma unroll
        for (int it = 0; it < 6; ++it) {
            int task = tid + it*256;
            if (task < 1360) {
                int pos = task >> 2, cq = task & 3;
                int py = pos / 34, pxx = pos - py*34;
                int gy = y0 - 1 + py, gx = x0 - 1 + pxx;
                bool ok = (gy >= 0) & (gy < HH) & (gx >= 0) & (gx < WW);
                const float* fp = feat + (size_t)(nb*64 + cg*16 + cq*4)*HWSZ + gy*WW + gx;
                f32x4 v;
                #pragma unroll
                for (int d = 0; d < 4; ++d) v[d] = ok ? fp[(size_t)d*HWSZ] : 0.f;
                *(f32x4*)&PT[pos*20 + cq*4] = v;
            }
        }
        __syncthreads();

        short8v CA[3][4];
        #pragma unroll
        for (int ch = 0; ch < 3; ++ch)
            #pragma unroll
            for (int oc = 0; oc < 4; ++oc)
                CA[ch][oc] = *(const short8v*)(coefa + (size_t)(((cg*3 + ch)*4 + oc)*64 + lane)*8);

        #pragma unroll
        for (int nf = 0; nf < 4; ++nf) {
            int gnf = wv*4 + nf, r = gnf >> 1, h = gnf & 1;
            int px = r*32 + 16*h + l15;
            float s[3][8];
            #pragma unroll
            for (int ch = 0; ch < 3; ++ch)
                #pragma unroll
                for (int j = 0; j < 8; ++j) s[ch][j] = 0.f;

            #pragma unroll
            for (int tap = 0; tap < 9; ++tap) {
                int ky = tap / 3, kx = tap - ky*3;
                int pos = (r + ky)*34 + 16*h + l15 + kx;
                const float* pp = &PT[pos*20 + c0];
                f32x4 pa = *(const f32x4*)pp;
                f32x4 pb = *(const f32x4*)(pp + 4);
                float ba0 = bf2f(BSH[px*56 + (m0*9 + tap)]);
                float ba1 = bf2f(BSH[px*56 + ((m0 + 2)*9 + tap)]);
                float ba2 = bf2f(BSH[px*56 + ((m0 + 4)*9 + tap)]);
                #pragma unroll
                for (int j = 0; j < 4; ++j) {
                    s[0][j]   = fmaf(ba0, pa[j], s[0][j]);
                    s[0][j+4] = fmaf(ba0, pb[j], s[0][j+4]);
                    s[1][j]   = fmaf(ba1, pa[j], s[1][j]);
                    s[1][j+4] = fmaf(ba1, pb[j], s[1][j+4]);
                    s[2][j]   = fmaf(ba2, pa[j], s[2][j]);
                    s[2][j+4] = fmaf(ba2, pb[j], s[2][j+4]);
                }
            }
            short8v B0, B1, B2;
            #pragma unroll
            for (int j = 0; j < 8; ++j) {
                B0[j] = (short)bhi(s[0][j]);
                B1[j] = (short)bhi(s[1][j]);
                B2[j] = (short)bhi(s[2][j]);
            }
            #pragma unroll
            for (int oc = 0; oc < 4; ++oc) {
                acc[oc][nf] = __builtin_amdgcn_mfma_f32_16x16x32_bf16(CA[0][oc], B0, acc[oc][nf], 0, 0, 0);
                acc[oc][nf] = __builtin_amdgcn_mfma_f32_16x16x32_bf16(CA[1][oc], B1, acc[oc][nf], 0, 0, 0);
                acc[oc][nf] = __builtin_amdgcn_mfma_f32_16x16x32_bf16(CA[2][oc], B2, acc[oc][nf], 0, 0, 0);
            }
        }
    }

    // epilogue: BN(+coef_bias)+ReLU -> u
    #pragma unroll
    for (int ocf = 0; ocf < 4; ++ocf)
        #pragma unroll
        for (int i = 0; i < 4; ++i) {
            int co = ocf*16 + l4*4 + i;
            float sc = bn[co], ofs = bn[64 + co];
            float* up = uout + (size_t)(nb*64 + co)*HWSZ;
            #pragma unroll
            for (int nf = 0; nf < 4; ++nf) {
                int gnf = wv*4 + nf, r = gnf >> 1, h = gnf & 1;
                int y = y0 + r, x = x0 + 16*h + l15;
                up[y*WW + x] = fmaxf(acc[ocf][nf][i]*sc + ofs, 0.f);
            }
        }
}

extern "C" void kernel_launch(void* const* d_in, const int* in_sizes, int n_in,
                              void* d_out, int out_size, void* d_ws, size_t ws_size,
                              hipStream_t stream) {
    const float* feat      = (const float*)d_in[0];
    const float* wgt       = (const float*)d_in[1];
    const float* w1        = (const float*)d_in[2];
    const float* b1        = (const float*)d_in[3];
    const float* w2        = (const float*)d_in[4];
    const float* b2        = (const float*)d_in[5];
    const float* coef      = (const float*)d_in[6];
    const float* coef_bias = (const float*)d_in[7];
    const float* brg       = (const float*)d_in[8];
    const float* brb       = (const float*)d_in[9];
    const float* brm       = (const float*)d_in[10];
    const float* brv       = (const float*)d_in[11];
    const float* w3        = (const float*)d_in[12];
    const float* g3        = (const float*)d_in[13];
    const float* b3        = (const float*)d_in[14];
    const float* m3        = (const float*)d_in[15];
    const float* v3        = (const float*)d_in[16];

    float* out = (float*)d_out;
    float* ws  = (float*)d_ws;
    unsigned short* bw = (unsigned short*)ws;

    prep_k<<<123, 256, 0, stream>>>(w1, w3, w2, coef, coef_bias,
                                    brg, brb, brm, brv, g3, b3, m3, v3, ws);

    dim3 grid(WW/32, HH/8, NN);   // (10, 30, 2)

    // conv1: t -> d_out
    convmfma_k<4, false><<<grid, 256, 0, stream>>>(
        feat, wgt, bw, b1, b1, out);

    // fuse2: u -> ws
    fuse2_k<<<grid, 256, 0, stream>>>(feat, out,
        bw + OFF_W2A/2, b2, bw + OFF_COEFA/2, ws + OFF_BN/4, ws + OFF_U/4);

    // conv3: d_out
    convmfma_k<2, true><<<grid, 256, 0, stream>>>(
        ws + OFF_U/4, ws + OFF_U/4, bw + OFF_BW3/2,
        ws + OFF_BN/4 + 128, ws + OFF_BN/4 + 192, out);
}

// Round 5
// 253.810 us; speedup vs baseline: 13.1058x; 1.0134x over previous
//
#include <hip/hip_runtime.h>
#include <math.h>

#define HH 240
#define WW 320
#define HWSZ (240*320)
#define NN 2

// Workspace layout (bytes)
#define OFF_BW1   0         // conv1 weight frags: 294912 B
#define OFF_BW3   294912    // conv3 weight frags: 147456 B
#define OFF_W2A   442368    // bases-GEMM A frags: 8192 B
#define OFF_COEFA 450560    // coef-GEMM A frags: 49152 B
#define OFF_BN    499712    // [sbr(64), bbr2(64), s3(64), o3(64)] f32
#define OFF_U     500736    // u: 2*64*76800 f32

typedef __attribute__((ext_vector_type(8))) short short8v;
typedef __attribute__((ext_vector_type(4))) float f32x4;

__device__ __forceinline__ unsigned short bhi(float x) {
    union { float f; unsigned u; } c; c.f = x; return (unsigned short)(c.u >> 16);
}
__device__ __forceinline__ float bf2f(unsigned short h) {
    union { float f; unsigned u; } c; c.u = ((unsigned)h) << 16; return c.f;
}

// ---------------- prep: weight frag packing + BN folds (unchanged layout) ----------------
__global__ void prep_k(const float* __restrict__ w1, const float* __restrict__ w3,
                       const float* __restrict__ w2, const float* __restrict__ coef,
                       const float* __restrict__ coef_bias,
                       const float* __restrict__ brg, const float* __restrict__ brb,
                       const float* __restrict__ brm, const float* __restrict__ brv,
                       const float* __restrict__ g3, const float* __restrict__ b3,
                       const float* __restrict__ m3, const float* __restrict__ v3,
                       float* __restrict__ ws) {
    int id = blockIdx.x * 256 + threadIdx.x;
    unsigned short* bw = (unsigned short*)ws;

    if (id < 18432) {   // conv1 weight frags (split hi/lo); frag f = g*8 + m*2 + half
        int l = id & 63; int f = id >> 6;
        int half = f & 1; f >>= 1;
        int m = f & 3;    f >>= 2;
        int t = f % 9, cc = f / 9;
        unsigned short v16[8];
        #pragma unroll
        for (int j = 0; j < 8; ++j) {
            int ci = cc*32 + (l>>4)*8 + j;
            int co = m*16 + (l&15);
            float v = w1[(co*128 + ci)*9 + t];
            unsigned short hi = bhi(v);
            v16[j] = half ? bhi(v - bf2f(hi)) : hi;
        }
        unsigned short* dst = bw + (size_t)(((cc*9 + t)*4 + m)*2 + half)*512 + l*8;
        #pragma unroll
        for (int j = 0; j < 8; ++j) dst[j] = v16[j];
        return;
    }
    id -= 18432;
    if (id < 9216) {    // conv3 weight frags
        int l = id & 63; int f = id >> 6;
        int half = f & 1; f >>= 1;
        int m = f & 3;    f >>= 2;
        int t = f % 9, cc = f / 9;
        unsigned short v16[8];
        #pragma unroll
        for (int j = 0; j < 8; ++j) {
            int ci = cc*32 + (l>>4)*8 + j;
            int co = m*16 + (l&15);
            float v = w3[(co*64 + ci)*9 + t];
            unsigned short hi = bhi(v);
            v16[j] = half ? bhi(v - bf2f(hi)) : hi;
        }
        unsigned short* dst = bw + OFF_BW3/2 + (size_t)(((cc*9 + t)*4 + m)*2 + half)*512 + l*8;
        #pragma unroll
        for (int j = 0; j < 8; ++j) dst[j] = v16[j];
        return;
    }
    id -= 9216;
    if (id < 512) {     // W2A frags
        int l = id & 63; int f = id >> 6;
        int mf = f & 3, kc = f >> 2;
        int row = mf*16 + (l & 15);
        unsigned short* dst = bw + OFF_W2A/2 + (size_t)((kc*4 + mf)*64 + l)*8;
        #pragma unroll
        for (int j = 0; j < 8; ++j) {
            int k = kc*32 + (l>>4)*8 + j;
            float v = (row < 54) ? w2[row*64 + k] : 0.f;
            dst[j] = bhi(v);
        }
        return;
    }
    id -= 512;
    if (id < 3072) {    // COEFA frags
        int l = id & 63; int f = id >> 6;
        int ocf = f & 3; int g2 = f >> 2;
        int ch = g2 % 3, cg = g2 / 3;
        int oc = ocf*16 + (l & 15);
        unsigned short* dst = bw + OFF_COEFA/2 + (size_t)((g2*4 + ocf)*64 + l)*8;
        #pragma unroll
        for (int j = 0; j < 8; ++j) {
            int k32 = (l>>4)*8 + j;
            int m = ch*2 + (k32 >> 4);
            int c = cg*16 + (k32 & 15);
            dst[j] = bhi(coef[oc*384 + c*6 + m]);
        }
        return;
    }
    id -= 3072;
    if (id < 64) {
        float s = brg[id] * rsqrtf(brv[id] + 1e-5f);
        ws[OFF_BN/4 + id]      = s;
        ws[OFF_BN/4 + 64 + id] = coef_bias[id]*s + brb[id] - brm[id]*s;
        return;
    }
    id -= 64;
    if (id < 64) {
        float s = g3[id] * rsqrtf(v3[id] + 1e-5f);
        ws[OFF_BN/4 + 128 + id] = s;
        ws[OFF_BN/4 + 192 + id] = b3[id] - m3[id]*s;
    }
}

// ---------------- MFMA conv 3x3, v2 ----------------
// Weights: global->LDS DMA (global_load_lds, 16B), cooperative (wave wv does frag
// slots 2wv,2wv+1), double-buffered per tap; one __syncthreads per tap (its
// vmcnt(0)+lgkmcnt(0) drain is the needed fence). All waves ds_read the shared copy.
// Inputs: T14 split — next chunk's 44 loads issued into pfv regs at chunk entry,
// converted to bf16 hi/lo and ds_written at the NEXT chunk entry.
template<int CHUNKS, bool HAS_SCALE>
__launch_bounds__(256, 2)
__global__ void convmfma_k(const float* __restrict__ in0, const float* __restrict__ in1,
                           const unsigned short* __restrict__ wfr,
                           const float* __restrict__ epiA, const float* __restrict__ epiB,
                           float* __restrict__ outp) {
    __shared__ unsigned long long AHI[3400], ALO[3400];   // 54400 B input tiles
    __shared__ unsigned short WBUF[2][4096];              // 16384 B weight dbuf
    const int tid = threadIdx.x;
    const int lane = tid & 63, wv = tid >> 6;
    const int l15 = lane & 15, l4 = lane >> 4;
    const int x0 = blockIdx.x * 32, y0 = blockIdx.y * 8;
    const int nb = blockIdx.z;
    const int NT = CHUNKS * 9;

    f32x4 acc[4][4];
    #pragma unroll
    for (int m = 0; m < 4; ++m)
        #pragma unroll
        for (int nf = 0; nf < 4; ++nf)
            acc[m][nf] = (f32x4){0.f, 0.f, 0.f, 0.f};

    f32x4 pfv[11];

    // issue global loads for chunk cc into pfv (stay in flight until converted)
    auto issue_inputs = [&](int cc) {
        const float* plane = (cc < 2) ? in0 + (size_t)(nb*64 + cc*32) * HWSZ
                                      : in1 + (size_t)(nb*64 + (cc-2)*32) * HWSZ;
        #pragma unroll
        for (int it = 0; it < 11; ++it) {
            int i = tid + it * 256;
            if (it < 10 || i < 2720) {
                int q = i / 340, p = i - q*340;
                int py = p / 34, px = p - py*34;
                int gy = y0 - 1 + py, gx = x0 - 1 + px;
                bool ok = (gy >= 0) & (gy < HH) & (gx >= 0) & (gx < WW);
                const float* sp = plane + (size_t)(q*4) * HWSZ + gy*WW + gx;
                f32x4 v;
                #pragma unroll
                for (int d = 0; d < 4; ++d) v[d] = ok ? sp[(size_t)d * HWSZ] : 0.f;
                pfv[it] = v;
            }
        }
    };

    // convert pfv -> bf16 hi/lo, write to LDS tile
    auto write_tile = [&]() {
        #pragma unroll
        for (int it = 0; it < 11; ++it) {
            int i = tid + it * 256;
            if (it < 10 || i < 2720) {
                int q = i / 340, p = i - q*340;
                unsigned long long Hv = 0, Lv = 0;
                #pragma unroll
                for (int d = 0; d < 4; ++d) {
                    float v = pfv[it][d];
                    unsigned short h  = bhi(v);
                    unsigned short lo = bhi(v - bf2f(h));
                    Hv |= ((unsigned long long)h)  << (16*d);
                    Lv |= ((unsigned long long)lo) << (16*d);
                }
                int widx = p*10 + q;       // 80B rows
                AHI[widx] = Hv;
                ALO[widx] = Lv;
            }
        }
    };

    // cooperative weight DMA for tap g into WBUF[buf]
    auto dma_tap = [&](int g, int buf) {
        #pragma unroll
        for (int k = 0; k < 2; ++k) {
            int slot = wv*2 + k;                       // wave-uniform
            const unsigned short* src = wfr + (size_t)(g*8 + slot)*512 + lane*8;
            __builtin_amdgcn_global_load_lds(
                (const __attribute__((address_space(1))) unsigned int*)src,
                (__attribute__((address_space(3))) unsigned int*)&WBUF[buf][slot*512],
                16, 0, 0);
        }
    };

    const char* AHIb = (const char*)AHI;
    const char* ALOb = (const char*)ALO;

    // prologue: chunk-0 inputs + tap-0 weights
    issue_inputs(0);
    dma_tap(0, 0);

    #pragma unroll
    for (int cc = 0; cc < CHUNKS; ++cc) {
        write_tile();                 // waits on pfv loads (compiler vmcnt)
        __syncthreads();              // tile + pending weight DMA visible
        if (cc + 1 < CHUNKS) issue_inputs(cc + 1);   // T14: ride under MFMA phase

        #pragma unroll
        for (int t = 0; t < 9; ++t) {
            const int g = cc*9 + t;
            const int buf = g & 1;
            if (g + 1 < NT) dma_tap(g + 1, buf ^ 1);

            // weights for this tap from shared LDS copy
            short8v WH[4], WL[4];
            #pragma unroll
            for (int m = 0; m < 4; ++m) {
                WH[m] = *(const short8v*)&WBUF[buf][(m*2    )*512 + lane*8];
                WL[m] = *(const short8v*)&WBUF[buf][(m*2 + 1)*512 + lane*8];
            }

            const int ky = t / 3, kx = t - ky*3;
            #pragma unroll
            for (int nf = 0; nf < 4; ++nf) {
                int gnf = wv*4 + nf;
                int r = gnf >> 1, h = gnf & 1;
                int off = ((r + ky)*34 + 16*h + l15 + kx)*80 + l4*16;
                short8v Ph = *(const short8v*)(AHIb + off);
                short8v Pl = *(const short8v*)(ALOb + off);
                #pragma unroll
                for (int m = 0; m < 4; ++m) {
                    acc[m][nf] = __builtin_amdgcn_mfma_f32_16x16x32_bf16(WH[m], Ph, acc[m][nf], 0, 0, 0);
                    acc[m][nf] = __builtin_amdgcn_mfma_f32_16x16x32_bf16(WL[m], Ph, acc[m][nf], 0, 0, 0);
                    acc[m][nf] = __builtin_amdgcn_mfma_f32_16x16x32_bf16(WH[m], Pl, acc[m][nf], 0, 0, 0);
                }
            }
            __syncthreads();          // drains DMA(g+1) (vmcnt0) + all readers of WBUF[buf]
        }
    }

    // epilogue: D row = co, col = px
    #pragma unroll
    for (int m = 0; m < 4; ++m) {
        #pragma unroll
        for (int i = 0; i < 4; ++i) {
            int co = m*16 + l4*4 + i;
            float sc  = HAS_SCALE ? epiA[co] : 1.0f;
            float ofs = HAS_SCALE ? epiB[co] : epiA[co];
            float* op = outp + (size_t)(nb*64 + co) * HWSZ;
            #pragma unroll
            for (int nf = 0; nf < 4; ++nf) {
                int gnf = wv*4 + nf;
                int r = gnf >> 1, h = gnf & 1;
                int y = y0 + r, x = x0 + 16*h + l15;
                op[y*WW + x] = fmaxf(acc[m][nf][i]*sc + ofs, 0.f);
            }
        }
    }
}

// ---------------- kernel 2 (MFMA): bases + einsum + coef + BN + ReLU -> u ----------------
__launch_bounds__(256, 2)
__global__ void fuse2_k(const float* __restrict__ feat, const float* __restrict__ tin,
                        const unsigned short* __restrict__ w2a,
                        const float* __restrict__ b2,
                        const unsigned short* __restrict__ coefa,
                        const float* __restrict__ bn,
                        float* __restrict__ uout) {
    __shared__ unsigned short BSH[256*56];   // bases bf16 [px][54 pad 56]
    __shared__ float PT[340*20];             // patches f32 [pos][16 ch pad 20]
    const int tid = threadIdx.x;
    const int lane = tid & 63, wv = tid >> 6;
    const int l15 = lane & 15, l4 = lane >> 4;
    const int x0 = blockIdx.x*32, y0 = blockIdx.y*8;
    const int nb = blockIdx.z;

    // ---- Phase A: bases ----
    short8v w2f[2][4];
    #pragma unroll
    for (int kc = 0; kc < 2; ++kc)
        #pragma unroll
        for (int mf = 0; mf < 4; ++mf)
            w2f[kc][mf] = *(const short8v*)(w2a + (size_t)((kc*4 + mf)*64 + lane)*8);

    f32x4 b2v[4];
    #pragma unroll
    for (int mf = 0; mf < 4; ++mf)
        #pragma unroll
        for (int i = 0; i < 4; ++i) {
            int row = mf*16 + l4*4 + i;
            b2v[mf][i] = (row < 54) ? b2[row] : 0.f;
        }

    #pragma unroll
    for (int nf = 0; nf < 4; ++nf) {
        int gnf = wv*4 + nf, r = gnf >> 1, h = gnf & 1;
        int y = y0 + r, x = x0 + 16*h + l15;
        const float* tp = tin + (size_t)nb*64*HWSZ + y*WW + x;
        short8v tf0, tf1;
        #pragma unroll
        for (int j = 0; j < 8; ++j) {
            tf0[j] = (short)bhi(tp[(size_t)(l4*8 + j) * HWSZ]);
            tf1[j] = (short)bhi(tp[(size_t)(32 + l4*8 + j) * HWSZ]);
        }
        int px = r*32 + 16*h + l15;
        #pragma unroll
        for (int mf = 0; mf < 4; ++mf) {
            f32x4 ab = (f32x4){0.f, 0.f, 0.f, 0.f};
            ab = __builtin_amdgcn_mfma_f32_16x16x32_bf16(w2f[0][mf], tf0, ab, 0, 0, 0);
            ab = __builtin_amdgcn_mfma_f32_16x16x32_bf16(w2f[1][mf], tf1, ab, 0, 0, 0);
            if (mf < 3 || l4 < 2) {
                unsigned long long w = 0;
                #pragma unroll
                for (int i = 0; i < 4; ++i)
                    w |= ((unsigned long long)bhi(ab[i] + b2v[mf][i])) << (16*i);
                *(unsigned long long*)&BSH[px*56 + mf*16 + l4*4] = w;
            }
        }
    }

    // ---- Phase B ----
    f32x4 acc[4][4];
    #pragma unroll
    for (int m = 0; m < 4; ++m)
        #pragma unroll
        for (int nf = 0; nf < 4; ++nf)
            acc[m][nf] = (f32x4){0.f, 0.f, 0.f, 0.f};

    const int c0 = (l4 & 1) * 8;
    const int m0 = l4 >> 1;

    #pragma unroll 1
    for (int cg = 0; cg < 4; ++cg) {
        __syncthreads();
        #pragma unroll
        for (int it = 0; it < 6; ++it) {
            int task = tid + it*256;
            if (task < 1360) {
                int pos = task >> 2, cq = task & 3;
                int py = pos / 34, pxx = pos - py*34;
                int gy = y0 - 1 + py, gx = x0 - 1 + pxx;
                bool ok = (gy >= 0) & (gy < HH) & (gx >= 0) & (gx < WW);
                const float* fp = feat + (size_t)(nb*64 + cg*16 + cq*4)*HWSZ + gy*WW + gx;
                f32x4 v;
                #pragma unroll
                for (int d = 0; d < 4; ++d) v[d] = ok ? fp[(size_t)d*HWSZ] : 0.f;
                *(f32x4*)&PT[pos*20 + cq*4] = v;
            }
        }
        __syncthreads();

        short8v CA[3][4];
        #pragma unroll
        for (int ch = 0; ch < 3; ++ch)
            #pragma unroll
            for (int oc = 0; oc < 4; ++oc)
                CA[ch][oc] = *(const short8v*)(coefa + (size_t)(((cg*3 + ch)*4 + oc)*64 + lane)*8);

        #pragma unroll
        for (int nf = 0; nf < 4; ++nf) {
            int gnf = wv*4 + nf, r = gnf >> 1, h = gnf & 1;
            int px = r*32 + 16*h + l15;
            float s[3][8];
            #pragma unroll
            for (int ch = 0; ch < 3; ++ch)
                #pragma unroll
                for (int j = 0; j < 8; ++j) s[ch][j] = 0.f;

            #pragma unroll
            for (int tap = 0; tap < 9; ++tap) {
                int ky = tap / 3, kx = tap - ky*3;
                int pos = (r + ky)*34 + 16*h + l15 + kx;
                const float* pp = &PT[pos*20 + c0];
                f32x4 pa = *(const f32x4*)pp;
                f32x4 pb = *(const f32x4*)(pp + 4);
                float ba0 = bf2f(BSH[px*56 + (m0*9 + tap)]);
                float ba1 = bf2f(BSH[px*56 + ((m0 + 2)*9 + tap)]);
                float ba2 = bf2f(BSH[px*56 + ((m0 + 4)*9 + tap)]);
                #pragma unroll
                for (int j = 0; j < 4; ++j) {
                    s[0][j]   = fmaf(ba0, pa[j], s[0][j]);
                    s[0][j+4] = fmaf(ba0, pb[j], s[0][j+4]);
                    s[1][j]   = fmaf(ba1, pa[j], s[1][j]);
                    s[1][j+4] = fmaf(ba1, pb[j], s[1][j+4]);
                    s[2][j]   = fmaf(ba2, pa[j], s[2][j]);
                    s[2][j+4] = fmaf(ba2, pb[j], s[2][j+4]);
                }
            }
            short8v B0, B1, B2;
            #pragma unroll
            for (int j = 0; j < 8; ++j) {
                B0[j] = (short)bhi(s[0][j]);
                B1[j] = (short)bhi(s[1][j]);
                B2[j] = (short)bhi(s[2][j]);
            }
            #pragma unroll
            for (int oc = 0; oc < 4; ++oc) {
                acc[oc][nf] = __builtin_amdgcn_mfma_f32_16x16x32_bf16(CA[0][oc], B0, acc[oc][nf], 0, 0, 0);
                acc[oc][nf] = __builtin_amdgcn_mfma_f32_16x16x32_bf16(CA[1][oc], B1, acc[oc][nf], 0, 0, 0);
                acc[oc][nf] = __builtin_amdgcn_mfma_f32_16x16x32_bf16(CA[2][oc], B2, acc[oc][nf], 0, 0, 0);
            }
        }
    }

    #pragma unroll
    for (int ocf = 0; ocf < 4; ++ocf)
        #pragma unroll
        for (int i = 0; i < 4; ++i) {
            int co = ocf*16 + l4*4 + i;
            float sc = bn[co], ofs = bn[64 + co];
            float* up = uout + (size_t)(nb*64 + co)*HWSZ;
            #pragma unroll
            for (int nf = 0; nf < 4; ++nf) {
                int gnf = wv*4 + nf, r = gnf >> 1, h = gnf & 1;
                int y = y0 + r, x = x0 + 16*h + l15;
                up[y*WW + x] = fmaxf(acc[ocf][nf][i]*sc + ofs, 0.f);
            }
        }
}

extern "C" void kernel_launch(void* const* d_in, const int* in_sizes, int n_in,
                              void* d_out, int out_size, void* d_ws, size_t ws_size,
                              hipStream_t stream) {
    const float* feat      = (const float*)d_in[0];
    const float* wgt       = (const float*)d_in[1];
    const float* w1        = (const float*)d_in[2];
    const float* b1        = (const float*)d_in[3];
    const float* w2        = (const float*)d_in[4];
    const float* b2        = (const float*)d_in[5];
    const float* coef      = (const float*)d_in[6];
    const float* coef_bias = (const float*)d_in[7];
    const float* brg       = (const float*)d_in[8];
    const float* brb       = (const float*)d_in[9];
    const float* brm       = (const float*)d_in[10];
    const float* brv       = (const float*)d_in[11];
    const float* w3        = (const float*)d_in[12];
    const float* g3        = (const float*)d_in[13];
    const float* b3        = (const float*)d_in[14];
    const float* m3        = (const float*)d_in[15];
    const float* v3        = (const float*)d_in[16];

    float* out = (float*)d_out;
    float* ws  = (float*)d_ws;
    unsigned short* bw = (unsigned short*)ws;

    prep_k<<<123, 256, 0, stream>>>(w1, w3, w2, coef, coef_bias,
                                    brg, brb, brm, brv, g3, b3, m3, v3, ws);

    dim3 grid(WW/32, HH/8, NN);   // (10, 30, 2)

    // conv1: t -> d_out
    convmfma_k<4, false><<<grid, 256, 0, stream>>>(
        feat, wgt, bw, b1, b1, out);

    // fuse2: u -> ws
    fuse2_k<<<grid, 256, 0, stream>>>(feat, out,
        bw + OFF_W2A/2, b2, bw + OFF_COEFA/2, ws + OFF_BN/4, ws + OFF_U/4);

    // conv3: d_out
    convmfma_k<2, true><<<grid, 256, 0, stream>>>(
        ws + OFF_U/4, ws + OFF_U/4, bw + OFF_BW3/2,
        ws + OFF_BN/4 + 128, ws + OFF_BN/4 + 192, out);
}